// Round 10
// baseline (242.045 us; speedup 1.0000x reference)
//
#include <hip/hip_runtime.h>
#include <math.h>

// Shapes fixed by the reference: B=2, N=32, L=4, ED=64, H=4, HD=16
#define EPS 1e-5f

#define AG_LOAD(p)     __hip_atomic_load((p), __ATOMIC_RELAXED, __HIP_MEMORY_SCOPE_AGENT)
#define AG_STORE(p, v) __hip_atomic_store((p), (v), __ATOMIC_RELAXED, __HIP_MEMORY_SCOPE_AGENT)

struct Params {
    const int* ei; const int* batch; int E;
    const float* W0; const float* b0; const float* Ws; const float* bs;
    const float* ln_g; const float* ln_b;
    const float* fW0; const float* fb0; const float* fWs; const float* fbs;
    const float* fln_g; const float* fln_b;
    const float* opW; const float* opb;
    float* hA; float* qA;    // h/q for layers 1 and 3
    float* hB; float* qB;    // h/q for layer 2
    float* xbuf;             // x rows, gtid-owned across dispatches
    float* Pmin; float* Poff; float* Pdg;  // [4 layers][512 blocks][64 e]
    int* bar;                // tail counter (zeroed by k0)
    float* out;              // 64
};

// ---------------------------------------------------------------------------
// K0: adjacency slabs + closed-form layer 0 (rank-1 LN) + pool partial 0 +
// lin -> h1/q1.  256-thread blocks (4 rows), LDS ~3 KB.
__launch_bounds__(256, 1)
__global__ void k0(Params p) {
    const int tid  = threadIdx.x;            // 0..255
    const int blk  = blockIdx.x;             // 0..511
    const int gtid = blk * 256 + tid;
    const int c    = gtid & 63;
    const int d    = c & 15;
    const int rl   = tid >> 6;               // 0..3
    const int row  = gtid >> 6;
    const int y    = row & 31;
    const int r0     = blk * 4;
    const int b_blk  = r0 >> 10;
    const int xi_blk = (r0 >> 5) & 31;
    const int y0     = r0 & 31;              // 0,4,...,28
    const int rld    = xi_blk - y0;          // diag row-in-block if in [0,4)

    __shared__ float xslab[32];      // adj[b_blk, xi_blk, a]
    __shared__ float yslab[128];     // adj[b_blk, a, y0+j] at [a*4+j]
    __shared__ float xu[256];
    __shared__ float xrow[256];

    if (blk == 0 && tid == 0) p.bar[0] = 0;

    if (tid < 32)  xslab[tid] = 0.0f;
    if (tid < 128) yslab[tid] = 0.0f;
    __syncthreads();
    #pragma unroll 1
    for (int e2 = tid; e2 < p.E; e2 += 256) {
        int e0 = p.ei[e2], e1 = p.ei[p.E + e2];
        int g  = p.batch[e0];
        if (g == b_blk) {
            int ls = e0 - g * 32, ld = e1 - g * 32;
            if (ls == xi_blk) atomicAdd(&xslab[ld], 1.0f);
            unsigned dy = (unsigned)(ld - y0);
            if (dy < 4u) atomicAdd(&yslab[ls * 4 + dy], 1.0f);
        }
    }
    __syncthreads();
    if (tid == 0) xslab[xi_blk] = 2.0f;
    if (tid < 4)  yslab[(y0 + tid) * 4 + tid] = 2.0f;   // diag a==y
    __syncthreads();

    // closed-form LN16 stats of rank-1 h = W*v + b
    const float gl = p.ln_g[d], bl = p.ln_b[d];
    float Wc = p.W0[c], bc = p.b0[c];
    float sW = Wc, sB = bc;
    #pragma unroll
    for (int m = 1; m < 16; m <<= 1) {
        sW += __shfl_xor(sW, m, 16);
        sB += __shfl_xor(sB, m, 16);
    }
    float Ac = Wc - sW * 0.0625f;
    float Bc = bc - sB * 0.0625f;
    float sAA = Ac * Ac, sAB = Ac * Bc, sBB = Bc * Bc;
    #pragma unroll
    for (int m = 1; m < 16; m <<= 1) {
        sAA += __shfl_xor(sAA, m, 16);
        sAB += __shfl_xor(sAB, m, 16);
        sBB += __shfl_xor(sBB, m, 16);
    }
    const float varW = sAA * 0.0625f, covWB = sAB * 0.0625f, varB = sBB * 0.0625f;
    const float adjv = xslab[y];

    // online-softmax attention from adj slabs (all LDS operands)
    float mrun = -1e30f, lrun = 0.0f, arun = 0.0f;
    #pragma unroll 1
    for (int a = 0; a < 32; ++a) {
        float vx = xslab[a];
        float vy = yslab[a * 4 + rl];
        float hx = fmaf(Wc, vx, bc);
        float hy = fmaf(Wc, vy, bc);
        float qx = fmaf(Ac, vx, Bc) *
                   rsqrtf(fmaf(fmaf(varW, vx, 2.0f * covWB), vx, varB) + EPS) * gl + bl;
        float qy = fmaf(Ac, vy, Bc) *
                   rsqrtf(fmaf(fmaf(varW, vy, 2.0f * covWB), vy, varB) + EPS) * gl + bl;
        float rdot = qx * qy;
        float pp   = hx * hy;
        float rsum = pp, rsq = pp * pp;
        #pragma unroll
        for (int m = 1; m < 16; m <<= 1) {
            rdot += __shfl_xor(rdot, m, 16);
            rsum += __shfl_xor(rsum, m, 16);
            rsq  += __shfl_xor(rsq,  m, 16);
        }
        float s     = rdot * 0.25f;
        float pmean = rsum * 0.0625f;
        float pvar  = fmaxf(rsq * 0.0625f - pmean * pmean, 0.0f);
        float nrm   = (pp - pmean) * rsqrtf(pvar + EPS) * gl;
        float nm  = fmaxf(mrun, s);
        float scl = __expf(mrun - nm);
        float e   = __expf(s - nm);
        lrun = lrun * scl + e;
        arun = arun * scl + e * nrm;
        mrun = nm;
    }
    xu[tid] = arun / lrun + bl;   // wave-local; softmax sums to 1 -> +bl once

    // fin (K=65) + LN64
    const float* Wr2 = p.fW0 + c * 65;
    float acc2 = fmaf(Wr2[0], adjv, p.fb0[c]);
    {
        const float* xw = xu + rl * 64;
        #pragma unroll 8
        for (int j = 0; j < 64; ++j) acc2 = fmaf(Wr2[1 + j], xw[j], acc2);
    }
    float t1 = acc2;
    #pragma unroll
    for (int m = 1; m < 64; m <<= 1) t1 += __shfl_xor(t1, m, 64);
    float mu = t1 * (1.0f / 64.0f);
    float dv2 = acc2 - mu;
    float t2 = dv2 * dv2;
    #pragma unroll
    for (int m = 1; m < 64; m <<= 1) t2 += __shfl_xor(t2, m, 64);
    float xnew = dv2 * rsqrtf(t2 * (1.0f / 64.0f) + EPS) * p.fln_g[c] + p.fln_b[c];
    xrow[tid]    = xnew;
    p.xbuf[gtid] = xnew;
    __syncthreads();

    // pool partial 0 (block's 4 rows)
    if (tid < 64) {
        float mn = 1e30f, off = -1e30f, dg = -1e30f;
        #pragma unroll
        for (int r2 = 0; r2 < 4; ++r2) {
            float v = xrow[r2 * 64 + tid];
            mn = fminf(mn, v);
            if (r2 == rld) dg = v; else off = fmaxf(off, v);
        }
        int o = blk * 64 + tid;
        p.Pmin[o] = mn; p.Poff[o] = off; p.Pdg[o] = dg;
    }

    // lin layer 1: h1 = x1 @ Ws[0].T + bs[0]; q1 = LN16 with ln[1]
    {
        const float4* W4 = (const float4*)(p.Ws + c * 64);
        const float4* X4 = (const float4*)(xrow + rl * 64);
        float acc = p.bs[c];
        #pragma unroll 4
        for (int j = 0; j < 16; ++j) {
            float4 w = W4[j], x = X4[j];
            acc += w.x * x.x + w.y * x.y + w.z * x.z + w.w * x.w;
        }
        p.hA[gtid] = acc;
        float s1 = acc;
        #pragma unroll
        for (int m = 1; m < 16; m <<= 1) s1 += __shfl_xor(s1, m, 16);
        float mean = s1 * 0.0625f;
        float dv = acc - mean;
        float s2 = dv * dv;
        #pragma unroll
        for (int m = 1; m < 16; m <<= 1) s2 += __shfl_xor(s2, m, 16);
        p.qA[gtid] = dv * rsqrtf(s2 * 0.0625f + EPS) * p.ln_g[16 + d] + p.ln_b[16 + d];
    }
}

// ---------------------------------------------------------------------------
// K(layer): attention + fin for `layer` (1..3), pool partial, then either
// lin->h/q for layer+1 (layer<3) or the tail-block epilogue (layer==3).
// 256-thread blocks; q/h slabs read straight from global (L1/L2-cached).
__launch_bounds__(256, 1)
__global__ void klayer(Params p, int layer, int is_last) {
    const int tid  = threadIdx.x;
    const int blk  = blockIdx.x;
    const int gtid = blk * 256 + tid;
    const int c    = gtid & 63;
    const int d    = c & 15;
    const int rl   = tid >> 6;
    const int row  = gtid >> 6;
    const int y    = row & 31;
    const int b    = row >> 10;
    const int r0     = blk * 4;
    const int b_blk  = r0 >> 10;
    const int xi_blk = (r0 >> 5) & 31;
    const int y0     = r0 & 31;
    const int rld    = xi_blk - y0;
    const int slab_off = (b_blk * 1024 + xi_blk * 32) * 64;

    const float* hin = (layer == 2) ? p.hB : p.hA;
    const float* qin = (layer == 2) ? p.qB : p.qA;
    float* hout = (layer == 1) ? p.hB : p.hA;   // layer2 overwrites hA (h1 dead)
    float* qout = (layer == 1) ? p.qB : p.qA;

    __shared__ float xrow[256], xu[256];
    __shared__ float sm_mn[512], sm_off[512], sm_dg[512];
    __shared__ float psum[256];
    __shared__ float vals[4];
    __shared__ float scores_s[64];
    __shared__ int tailflag;

    xrow[tid] = p.xbuf[gtid];

    const float gl = p.ln_g[layer * 16 + d], bl = p.ln_b[layer * 16 + d];
    const float* qyb = qin + (b * 1024 + y) * 64 + c;   // + a*2048
    const float* hyb = hin + (b * 1024 + y) * 64 + c;
    const float* qxb = qin + slab_off + c;              // + a*64
    const float* hxb = hin + slab_off + c;

    // ---- attention: online softmax, 4 chunks of 8 a's, all-global loads ----
    float mrun = -1e30f, lrun = 0.0f, arun = 0.0f;
    #pragma unroll 1
    for (int ch = 0; ch < 4; ++ch) {
        float qv8[8], hv8[8], qx8[8], hx8[8];
        const int a0 = ch * 8;
        #pragma unroll
        for (int k = 0; k < 8; ++k) {
            qv8[k] = qyb[(a0 + k) * 2048];
            hv8[k] = hyb[(a0 + k) * 2048];
            qx8[k] = qxb[(a0 + k) * 64];
            hx8[k] = hxb[(a0 + k) * 64];
        }
        #pragma unroll
        for (int k = 0; k < 8; ++k) {
            float rdot = qx8[k] * qv8[k];
            float pp   = hx8[k] * hv8[k];
            float rsum = pp, rsq = pp * pp;
            #pragma unroll
            for (int m = 1; m < 16; m <<= 1) {
                rdot += __shfl_xor(rdot, m, 16);
                rsum += __shfl_xor(rsum, m, 16);
                rsq  += __shfl_xor(rsq,  m, 16);
            }
            float s     = rdot * 0.25f;
            float pmean = rsum * 0.0625f;
            float pvar  = fmaxf(rsq * 0.0625f - pmean * pmean, 0.0f);
            float nrm   = (pp - pmean) * rsqrtf(pvar + EPS) * gl;
            float nm  = fmaxf(mrun, s);
            float scl = __expf(mrun - nm);
            float e   = __expf(s - nm);
            lrun = lrun * scl + e;
            arun = arun * scl + e * nrm;
            mrun = nm;
        }
    }
    xu[tid] = arun / lrun + bl;   // wave-local

    // ---- fin: y = concat([x, xu]) @ fW.T + fb, LN64 (wave-local LDS reads) ----
    float acc2 = p.fbs[(layer - 1) * 64 + c];
    {
        const float4* W4 = (const float4*)(p.fWs + (layer - 1) * 8192 + c * 128);
        const float4* Xa = (const float4*)(xrow + rl * 64);
        const float4* Xb = (const float4*)(xu + rl * 64);
        #pragma unroll 4
        for (int j = 0; j < 16; ++j) {
            float4 w = W4[j], x = Xa[j];
            acc2 += w.x * x.x + w.y * x.y + w.z * x.z + w.w * x.w;
        }
        #pragma unroll 4
        for (int j = 0; j < 16; ++j) {
            float4 w = W4[16 + j], x = Xb[j];
            acc2 += w.x * x.x + w.y * x.y + w.z * x.z + w.w * x.w;
        }
    }
    float t1 = acc2;
    #pragma unroll
    for (int m = 1; m < 64; m <<= 1) t1 += __shfl_xor(t1, m, 64);
    float mu = t1 * (1.0f / 64.0f);
    float dv2 = acc2 - mu;
    float t2 = dv2 * dv2;
    #pragma unroll
    for (int m = 1; m < 64; m <<= 1) t2 += __shfl_xor(t2, m, 64);
    float xnew = dv2 * rsqrtf(t2 * (1.0f / 64.0f) + EPS) *
                 p.fln_g[layer * 64 + c] + p.fln_b[layer * 64 + c];
    xrow[tid] = xnew;            // same-wave overwrite after same-wave read
    if (!is_last) p.xbuf[gtid] = xnew;
    __syncthreads();

    // ---- pool partial for this layer (block's 4 rows) ----
    if (tid < 64) {
        float mn = 1e30f, off = -1e30f, dg = -1e30f;
        #pragma unroll
        for (int r2 = 0; r2 < 4; ++r2) {
            float v = xrow[r2 * 64 + tid];
            mn = fminf(mn, v);
            if (r2 == rld) dg = v; else off = fmaxf(off, v);
        }
        int o = layer * 32768 + blk * 64 + tid;
        if (is_last) {   // must be LLC-visible within this dispatch (tail reads)
            AG_STORE(&p.Pmin[o], mn); AG_STORE(&p.Poff[o], off); AG_STORE(&p.Pdg[o], dg);
        } else {
            p.Pmin[o] = mn; p.Poff[o] = off; p.Pdg[o] = dg;
        }
    }

    if (!is_last) {
        // lin layer+1: h = x @ Ws[layer].T + bs[layer]; q = LN16 with ln[layer+1]
        const float4* W4 = (const float4*)(p.Ws + layer * 4096 + c * 64);
        const float4* X4 = (const float4*)(xrow + rl * 64);
        float acc = p.bs[layer * 64 + c];
        #pragma unroll 4
        for (int j = 0; j < 16; ++j) {
            float4 w = W4[j], x = X4[j];
            acc += w.x * x.x + w.y * x.y + w.z * x.z + w.w * x.w;
        }
        hout[gtid] = acc;
        float s1 = acc;
        #pragma unroll
        for (int m = 1; m < 16; m <<= 1) s1 += __shfl_xor(s1, m, 16);
        float mean = s1 * 0.0625f;
        float dv = acc - mean;
        float s2 = dv * dv;
        #pragma unroll
        for (int m = 1; m < 16; m <<= 1) s2 += __shfl_xor(s2, m, 16);
        qout[gtid] = dv * rsqrtf(s2 * 0.0625f + EPS) *
                     p.ln_g[(layer + 1) * 16 + d] + p.ln_b[(layer + 1) * 16 + d];
        return;
    }

    // ---- tail-block: 512th arriver runs the epilogue ----
    if (tid == 0) {
        int r = __hip_atomic_fetch_add(p.bar, 1, __ATOMIC_RELAXED,
                                       __HIP_MEMORY_SCOPE_AGENT);
        tailflag = (r == 511) ? 1 : 0;
    }
    __syncthreads();
    if (!tailflag) return;

    // ================= epilogue (tail block only, 256 threads) =================
    // stage 1: reduce 256 block-partials per (layer, graph, e) — 512 targets
    #pragma unroll 1
    for (int t = tid; t < 512; t += 256) {
        int l = t >> 7, bb = (t >> 6) & 1, e = t & 63;
        float mn = 1e30f, off = -1e30f, dg = -1e30f;
        int base = l * 32768 + bb * 256 * 64 + e;
        if (l == 3) {
            #pragma unroll 4
            for (int k = 0; k < 256; ++k) {
                int o = base + k * 64;
                mn  = fminf(mn,  AG_LOAD(&p.Pmin[o]));
                off = fmaxf(off, AG_LOAD(&p.Poff[o]));
                dg  = fmaxf(dg,  AG_LOAD(&p.Pdg[o]));
            }
        } else {
            #pragma unroll 4
            for (int k = 0; k < 256; ++k) {
                int o = base + k * 64;
                mn  = fminf(mn,  p.Pmin[o]);
                off = fmaxf(off, p.Poff[o]);
                dg  = fmaxf(dg,  p.Pdg[o]);
            }
        }
        sm_mn[t] = mn; sm_off[t] = off; sm_dg[t] = dg;
    }
    __syncthreads();
    // stage 2: per-layer val = |global max_diag - global min|
    if (tid < 4) {
        float gmx = -1e30f, gmn = 1e30f;
        #pragma unroll 1
        for (int i2 = 0; i2 < 128; ++i2) {
            gmx = fmaxf(gmx, sm_dg[tid * 128 + i2]);
            gmn = fminf(gmn, sm_mn[tid * 128 + i2]);
        }
        vals[tid] = fabsf(gmx - gmn);
    }
    __syncthreads();
    // stage 3: partial GEMV  (tid = bb*128 + cc*4 + pp)
    {
        int bb = tid >> 7, cc = (tid >> 2) & 31, pp = tid & 3;
        float a2 = 0.0f;
        #pragma unroll 1
        for (int l = 0; l < 4; ++l) {
            float val = vals[l];
            const float* Wr = p.opW + l * 4096 + cc * 128;
            int base = l * 128 + bb * 64;
            #pragma unroll 1
            for (int j = pp * 32; j < pp * 32 + 32; ++j) {
                float pv;
                if (j < 64) pv = sm_dg[base + j];
                else        pv = fmaxf(sm_off[base + j - 64], sm_dg[base + j - 64] - val);
                a2 = fmaf(Wr[j], pv, a2);
            }
        }
        psum[tid] = a2;
    }
    __syncthreads();
    if (tid < 64) {
        int bb = tid >> 5, cc = tid & 31;
        float a2 = 0.0f;
        #pragma unroll
        for (int l = 0; l < 4; ++l) a2 += p.opb[l * 32 + cc];
        #pragma unroll
        for (int pp = 0; pp < 4; ++pp) a2 += psum[bb * 128 + cc * 4 + pp];
        scores_s[tid] = a2;
    }
    __syncthreads();
    if (tid < 32) {
        float sA = scores_s[tid], sB = scores_s[32 + tid];
        float mu2 = 0.5f * (sA + sB);
        float va = 0.5f * ((sA - mu2) * (sA - mu2) + (sB - mu2) * (sB - mu2));
        float inv = rsqrtf(va + EPS);
        p.out[tid]      = (sA - mu2) * inv;
        p.out[32 + tid] = (sB - mu2) * inv;
    }
}

// ---------------------------------------------------------------------------
extern "C" void kernel_launch(void* const* d_in, const int* in_sizes, int n_in,
                              void* d_out, int out_size, void* d_ws, size_t ws_size,
                              hipStream_t stream) {
    Params prm;
    prm.ei    = (const int*)d_in[0];
    prm.batch = (const int*)d_in[1];
    prm.E     = in_sizes[0] / 2;
    prm.W0    = (const float*)d_in[2];
    prm.b0    = (const float*)d_in[3];
    prm.Ws    = (const float*)d_in[4];
    prm.bs    = (const float*)d_in[5];
    prm.ln_g  = (const float*)d_in[6];
    prm.ln_b  = (const float*)d_in[7];
    prm.fW0   = (const float*)d_in[8];
    prm.fb0   = (const float*)d_in[9];
    prm.fWs   = (const float*)d_in[10];
    prm.fbs   = (const float*)d_in[11];
    prm.fln_g = (const float*)d_in[12];
    prm.fln_b = (const float*)d_in[13];
    prm.opW   = (const float*)d_in[14];
    prm.opb   = (const float*)d_in[15];

    float* ws = (float*)d_ws;
    prm.hA    = ws;                   // 131072 each
    prm.qA    = prm.hA   + 131072;
    prm.hB    = prm.qA   + 131072;
    prm.qB    = prm.hB   + 131072;
    prm.xbuf  = prm.qB   + 131072;
    prm.Pmin  = prm.xbuf + 131072;    // 4*32768 each
    prm.Poff  = prm.Pmin + 131072;
    prm.Pdg   = prm.Poff + 131072;
    prm.bar   = (int*)(prm.Pdg + 131072);
    prm.out   = (float*)d_out;

    k0<<<512, 256, 0, stream>>>(prm);
    klayer<<<512, 256, 0, stream>>>(prm, 1, 0);
    klayer<<<512, 256, 0, stream>>>(prm, 2, 0);
    klayer<<<512, 256, 0, stream>>>(prm, 3, 1);
}

// Round 11
// 212.646 us; speedup vs baseline: 1.1383x; 1.1383x over previous
//
#include <hip/hip_runtime.h>
#include <math.h>

// Shapes fixed by the reference: B=2, N=32, L=4, ED=64, H=4, HD=16
#define EPS 1e-5f

#define AG_LOAD(p)     __hip_atomic_load((p), __ATOMIC_RELAXED, __HIP_MEMORY_SCOPE_AGENT)
#define AG_STORE(p, v) __hip_atomic_store((p), (v), __ATOMIC_RELAXED, __HIP_MEMORY_SCOPE_AGENT)

struct Params {
    const int* ei; const int* batch; int E;
    const float* W0; const float* b0; const float* Ws; const float* bs;
    const float* ln_g; const float* ln_b;
    const float* fW0; const float* fb0; const float* fWs; const float* fbs;
    const float* fln_g; const float* fln_b;
    const float* opW; const float* opb;
    float* hA; float* qA;      // h/q rows (b,x,y) for layers 1 and 3
    float* hB; float* qB;      // layer 2
    float* hAT; float* qAT;    // transposed (b,y,x) copies for layers 1 and 3
    float* hBT; float* qBT;    // layer 2
    float* xbuf;               // x rows, gtid-owned across dispatches
    float* Pmin; float* Poff; float* Pdg;  // [4 layers][256 blocks][64 e]
    int* bar;                  // tail counter (zeroed by k0)
    float* out;                // 64
};

// ---------------------------------------------------------------------------
// K0: adjacency slabs + closed-form layer 0 (rank-1 LN) + pool partial 0 +
// lin -> h1/q1 (both layouts).  512-thread blocks, 8 rows each.
__launch_bounds__(512, 1)
__global__ void k0(Params p) {
    const int tid  = threadIdx.x;
    const int blk  = blockIdx.x;
    const int gtid = blk * 512 + tid;
    const int c    = gtid & 63;
    const int d    = c & 15;
    const int rl   = tid >> 6;
    const int row  = gtid >> 6;
    const int y    = row & 31;
    const int r0     = blk * 8;
    const int b_blk  = r0 >> 10;
    const int xi_blk = (r0 >> 5) & 31;
    const int y0     = r0 & 31;
    const int rld    = xi_blk - y0;

    __shared__ float xslab[32];      // adj[b_blk, xi_blk, a]
    __shared__ float yslab[256];     // adj[b_blk, a, y0+j] at [a*8+j]
    __shared__ float xu[512];
    __shared__ float xrow[512];

    if (blk == 0 && tid == 0) p.bar[0] = 0;

    if (tid < 32)  xslab[tid] = 0.0f;
    if (tid < 256) yslab[tid] = 0.0f;
    __syncthreads();
    #pragma unroll 1
    for (int e2 = tid; e2 < p.E; e2 += 512) {
        int e0 = p.ei[e2], e1 = p.ei[p.E + e2];
        int g  = p.batch[e0];
        if (g == b_blk) {
            int ls = e0 - g * 32, ld = e1 - g * 32;
            if (ls == xi_blk) atomicAdd(&xslab[ld], 1.0f);
            unsigned dy = (unsigned)(ld - y0);
            if (dy < 8u) atomicAdd(&yslab[ls * 8 + dy], 1.0f);
        }
    }
    __syncthreads();
    if (tid == 0) xslab[xi_blk] = 2.0f;
    if (tid < 8)  yslab[(y0 + tid) * 8 + tid] = 2.0f;   // diag a==y
    __syncthreads();

    // closed-form LN16 stats of rank-1 h = W*v + b
    const float gl = p.ln_g[d], bl = p.ln_b[d];
    float Wc = p.W0[c], bc = p.b0[c];
    float sW = Wc, sB = bc;
    #pragma unroll
    for (int m = 1; m < 16; m <<= 1) {
        sW += __shfl_xor(sW, m, 16);
        sB += __shfl_xor(sB, m, 16);
    }
    float Ac = Wc - sW * 0.0625f;
    float Bc = bc - sB * 0.0625f;
    float sAA = Ac * Ac, sAB = Ac * Bc, sBB = Bc * Bc;
    #pragma unroll
    for (int m = 1; m < 16; m <<= 1) {
        sAA += __shfl_xor(sAA, m, 16);
        sAB += __shfl_xor(sAB, m, 16);
        sBB += __shfl_xor(sBB, m, 16);
    }
    const float varW = sAA * 0.0625f, covWB = sAB * 0.0625f, varB = sBB * 0.0625f;
    const float adjv = xslab[y];

    // online-softmax attention from adj slabs (all LDS operands)
    float mrun = -1e30f, lrun = 0.0f, arun = 0.0f;
    #pragma unroll 1
    for (int a = 0; a < 32; ++a) {
        float vx = xslab[a];
        float vy = yslab[a * 8 + rl];
        float hx = fmaf(Wc, vx, bc);
        float hy = fmaf(Wc, vy, bc);
        float qx = fmaf(Ac, vx, Bc) *
                   rsqrtf(fmaf(fmaf(varW, vx, 2.0f * covWB), vx, varB) + EPS) * gl + bl;
        float qy = fmaf(Ac, vy, Bc) *
                   rsqrtf(fmaf(fmaf(varW, vy, 2.0f * covWB), vy, varB) + EPS) * gl + bl;
        float rdot = qx * qy;
        float pp   = hx * hy;
        float rsum = pp, rsq = pp * pp;
        #pragma unroll
        for (int m = 1; m < 16; m <<= 1) {
            rdot += __shfl_xor(rdot, m, 16);
            rsum += __shfl_xor(rsum, m, 16);
            rsq  += __shfl_xor(rsq,  m, 16);
        }
        float s     = rdot * 0.25f;
        float pmean = rsum * 0.0625f;
        float pvar  = fmaxf(rsq * 0.0625f - pmean * pmean, 0.0f);
        float nrm   = (pp - pmean) * rsqrtf(pvar + EPS) * gl;
        float nm  = fmaxf(mrun, s);
        float scl = __expf(mrun - nm);
        float e   = __expf(s - nm);
        lrun = lrun * scl + e;
        arun = arun * scl + e * nrm;
        mrun = nm;
    }
    xu[tid] = arun / lrun + bl;

    // fin (K=65) + LN64
    const float* Wr2 = p.fW0 + c * 65;
    float acc2 = fmaf(Wr2[0], adjv, p.fb0[c]);
    {
        const float* xw = xu + rl * 64;
        #pragma unroll 8
        for (int j = 0; j < 64; ++j) acc2 = fmaf(Wr2[1 + j], xw[j], acc2);
    }
    float t1 = acc2;
    #pragma unroll
    for (int m = 1; m < 64; m <<= 1) t1 += __shfl_xor(t1, m, 64);
    float mu = t1 * (1.0f / 64.0f);
    float dv2 = acc2 - mu;
    float t2 = dv2 * dv2;
    #pragma unroll
    for (int m = 1; m < 64; m <<= 1) t2 += __shfl_xor(t2, m, 64);
    float xnew = dv2 * rsqrtf(t2 * (1.0f / 64.0f) + EPS) * p.fln_g[c] + p.fln_b[c];
    xrow[tid]    = xnew;
    p.xbuf[gtid] = xnew;
    __syncthreads();

    // pool partial 0
    if (tid < 64) {
        float mn = 1e30f, off = -1e30f, dg = -1e30f;
        #pragma unroll
        for (int r2 = 0; r2 < 8; ++r2) {
            float v = xrow[r2 * 64 + tid];
            mn = fminf(mn, v);
            if (r2 == rld) dg = v; else off = fmaxf(off, v);
        }
        int o = blk * 64 + tid;
        p.Pmin[o] = mn; p.Poff[o] = off; p.Pdg[o] = dg;
    }

    // lin layer 1: h1 = x1 @ Ws[0].T + bs[0]; q1 = LN16 with ln[1]
    {
        const float4* W4 = (const float4*)(p.Ws + c * 64);
        const float4* X4 = (const float4*)(xrow + rl * 64);
        float acc = p.bs[c];
        #pragma unroll 4
        for (int j = 0; j < 16; ++j) {
            float4 w = W4[j], x = X4[j];
            acc += w.x * x.x + w.y * x.y + w.z * x.z + w.w * x.w;
        }
        float s1 = acc;
        #pragma unroll
        for (int m = 1; m < 16; m <<= 1) s1 += __shfl_xor(s1, m, 16);
        float mean = s1 * 0.0625f;
        float dv = acc - mean;
        float s2 = dv * dv;
        #pragma unroll
        for (int m = 1; m < 16; m <<= 1) s2 += __shfl_xor(s2, m, 16);
        float qv = dv * rsqrtf(s2 * 0.0625f + EPS) * p.ln_g[16 + d] + p.ln_b[16 + d];
        // dual-layout stores (row-major + transposed (b,y,x))
        const int xi = xi_blk;
        const int tr = ((row >> 10) * 1024 + y * 32 + xi) * 64 + c;
        p.hA[gtid] = acc;  p.qA[gtid] = qv;
        p.hAT[tr]  = acc;  p.qAT[tr]  = qv;
    }
}

// ---------------------------------------------------------------------------
// K(layer): attention + fin for `layer` (1..3), pool partial, then either
// lin->h/q for layer+1 (layer<3) or the tail-block epilogue (layer==3).
// y-side loads come from the TRANSPOSED h/q copies (contiguous 8 KB slab).
__launch_bounds__(512, 1)
__global__ void klayer(Params p, int layer, int is_last) {
    const int tid  = threadIdx.x;
    const int blk  = blockIdx.x;
    const int gtid = blk * 512 + tid;
    const int c    = gtid & 63;
    const int d    = c & 15;
    const int rl   = tid >> 6;
    const int row  = gtid >> 6;
    const int y    = row & 31;
    const int xi   = (row >> 5) & 31;
    const int b    = row >> 10;
    const int r0     = blk * 8;
    const int b_blk  = r0 >> 10;
    const int xi_blk = (r0 >> 5) & 31;
    const int y0     = r0 & 31;
    const int rld    = xi_blk - y0;
    const int slab_off = (b_blk * 1024 + xi_blk * 32) * 64;

    const float* hin  = (layer == 2) ? p.hB  : p.hA;
    const float* qin  = (layer == 2) ? p.qB  : p.qA;
    const float* hinT = (layer == 2) ? p.hBT : p.hAT;
    const float* qinT = (layer == 2) ? p.qBT : p.qAT;
    float* hout  = (layer == 1) ? p.hB  : p.hA;
    float* qout  = (layer == 1) ? p.qB  : p.qA;
    float* houtT = (layer == 1) ? p.hBT : p.hAT;
    float* qoutT = (layer == 1) ? p.qBT : p.qAT;

    __shared__ float qx_s[2048], hx_s[2048];
    __shared__ float xrow[512], xu[512];
    __shared__ float sm_mn[512], sm_off[512], sm_dg[512];
    __shared__ float psum[512];
    __shared__ float vals[4];
    __shared__ float scores_s[64];
    __shared__ int tailflag;

    // ---- staging: x row + x-slabs to LDS; y-slab to registers (contiguous) ----
    float xv = p.xbuf[gtid];
    float4 qs = ((const float4*)(qin + slab_off))[tid];
    float4 hs = ((const float4*)(hin + slab_off))[tid];
    const float* qyT = qinT + (b * 1024 + y * 32) * 64 + c;   // + a*64
    const float* hyT = hinT + (b * 1024 + y * 32) * 64 + c;
    float qyv[32], hyv[32];
    #pragma unroll
    for (int a = 0; a < 32; ++a) {
        qyv[a] = qyT[a * 64];
        hyv[a] = hyT[a * 64];
    }
    xrow[tid] = xv;
    ((float4*)qx_s)[tid] = qs;
    ((float4*)hx_s)[tid] = hs;
    __syncthreads();

    const float gl = p.ln_g[layer * 16 + d], bl = p.ln_b[layer * 16 + d];
    float sarr[32], narr[32];
    #pragma unroll
    for (int a = 0; a < 32; ++a) {
        float qxv = qx_s[a * 64 + c];
        float hxv = hx_s[a * 64 + c];
        float rdot = qxv * qyv[a];
        float pp   = hxv * hyv[a];
        float rsum = pp, rsq = pp * pp;
        #pragma unroll
        for (int m = 1; m < 16; m <<= 1) {
            rdot += __shfl_xor(rdot, m, 16);
            rsum += __shfl_xor(rsum, m, 16);
            rsq  += __shfl_xor(rsq,  m, 16);
        }
        sarr[a] = rdot * 0.25f;
        float pmean = rsum * 0.0625f;
        float pvar  = fmaxf(rsq * 0.0625f - pmean * pmean, 0.0f);
        narr[a] = (pp - pmean) * rsqrtf(pvar + EPS) * gl;
    }
    float mx = sarr[0];
    #pragma unroll
    for (int a = 1; a < 32; ++a) mx = fmaxf(mx, sarr[a]);
    float lsum = 0.0f, asum = 0.0f;
    #pragma unroll
    for (int a = 0; a < 32; ++a) {
        float ee = __expf(sarr[a] - mx);
        lsum += ee;
        asum = fmaf(ee, narr[a], asum);
    }
    xu[tid] = asum / lsum + bl;   // wave-local

    // ---- fin: y = concat([x, xu]) @ fW.T + fb, LN64 ----
    float acc2 = p.fbs[(layer - 1) * 64 + c];
    {
        const float4* W4 = (const float4*)(p.fWs + (layer - 1) * 8192 + c * 128);
        const float4* Xa = (const float4*)(xrow + rl * 64);
        const float4* Xb = (const float4*)(xu + rl * 64);
        #pragma unroll 4
        for (int j = 0; j < 16; ++j) {
            float4 w = W4[j], x = Xa[j];
            acc2 += w.x * x.x + w.y * x.y + w.z * x.z + w.w * x.w;
        }
        #pragma unroll 4
        for (int j = 0; j < 16; ++j) {
            float4 w = W4[16 + j], x = Xb[j];
            acc2 += w.x * x.x + w.y * x.y + w.z * x.z + w.w * x.w;
        }
    }
    float t1 = acc2;
    #pragma unroll
    for (int m = 1; m < 64; m <<= 1) t1 += __shfl_xor(t1, m, 64);
    float mu = t1 * (1.0f / 64.0f);
    float dv2 = acc2 - mu;
    float t2 = dv2 * dv2;
    #pragma unroll
    for (int m = 1; m < 64; m <<= 1) t2 += __shfl_xor(t2, m, 64);
    float xnew = dv2 * rsqrtf(t2 * (1.0f / 64.0f) + EPS) *
                 p.fln_g[layer * 64 + c] + p.fln_b[layer * 64 + c];
    xrow[tid] = xnew;            // same-wave overwrite after same-wave read
    if (!is_last) p.xbuf[gtid] = xnew;
    __syncthreads();

    // ---- pool partial for this layer ----
    if (tid < 64) {
        float mn = 1e30f, off = -1e30f, dg = -1e30f;
        #pragma unroll
        for (int r2 = 0; r2 < 8; ++r2) {
            float v = xrow[r2 * 64 + tid];
            mn = fminf(mn, v);
            if (r2 == rld) dg = v; else off = fmaxf(off, v);
        }
        int o = layer * 16384 + blk * 64 + tid;
        if (is_last) {   // must be LLC-visible within this dispatch (tail reads)
            AG_STORE(&p.Pmin[o], mn); AG_STORE(&p.Poff[o], off); AG_STORE(&p.Pdg[o], dg);
        } else {
            p.Pmin[o] = mn; p.Poff[o] = off; p.Pdg[o] = dg;
        }
    }

    if (!is_last) {
        // lin layer+1: h = x @ Ws[layer].T + bs[layer]; q = LN16 with ln[layer+1]
        const float4* W4 = (const float4*)(p.Ws + layer * 4096 + c * 64);
        const float4* X4 = (const float4*)(xrow + rl * 64);
        float acc = p.bs[layer * 64 + c];
        #pragma unroll 4
        for (int j = 0; j < 16; ++j) {
            float4 w = W4[j], x = X4[j];
            acc += w.x * x.x + w.y * x.y + w.z * x.z + w.w * x.w;
        }
        float s1 = acc;
        #pragma unroll
        for (int m = 1; m < 16; m <<= 1) s1 += __shfl_xor(s1, m, 16);
        float mean = s1 * 0.0625f;
        float dv = acc - mean;
        float s2 = dv * dv;
        #pragma unroll
        for (int m = 1; m < 16; m <<= 1) s2 += __shfl_xor(s2, m, 16);
        float qv = dv * rsqrtf(s2 * 0.0625f + EPS) *
                   p.ln_g[(layer + 1) * 16 + d] + p.ln_b[(layer + 1) * 16 + d];
        const int tr = (b * 1024 + y * 32 + xi) * 64 + c;
        hout[gtid] = acc;  qout[gtid] = qv;
        houtT[tr]  = acc;  qoutT[tr]  = qv;
        return;
    }

    // ---- tail-block: 256th arriver runs the epilogue ----
    if (tid == 0) {
        int r = __hip_atomic_fetch_add(p.bar, 1, __ATOMIC_RELAXED,
                                       __HIP_MEMORY_SCOPE_AGENT);
        tailflag = (r == 255) ? 1 : 0;
    }
    __syncthreads();
    if (!tailflag) return;

    // ================= epilogue (tail block only) =================
    {
        int l = tid >> 7, bb = (tid >> 6) & 1, e = tid & 63;
        float mn = 1e30f, off = -1e30f, dg = -1e30f;
        int base = l * 16384 + bb * 128 * 64 + e;
        if (l == 3) {
            #pragma unroll 4
            for (int k = 0; k < 128; ++k) {
                int o = base + k * 64;
                mn  = fminf(mn,  AG_LOAD(&p.Pmin[o]));
                off = fmaxf(off, AG_LOAD(&p.Poff[o]));
                dg  = fmaxf(dg,  AG_LOAD(&p.Pdg[o]));
            }
        } else {
            #pragma unroll 4
            for (int k = 0; k < 128; ++k) {
                int o = base + k * 64;
                mn  = fminf(mn,  p.Pmin[o]);
                off = fmaxf(off, p.Poff[o]);
                dg  = fmaxf(dg,  p.Pdg[o]);
            }
        }
        sm_mn[tid] = mn; sm_off[tid] = off; sm_dg[tid] = dg;
    }
    __syncthreads();
    if (tid < 4) {
        float gmx = -1e30f, gmn = 1e30f;
        #pragma unroll 1
        for (int i2 = 0; i2 < 128; ++i2) {
            gmx = fmaxf(gmx, sm_dg[tid * 128 + i2]);
            gmn = fminf(gmn, sm_mn[tid * 128 + i2]);
        }
        vals[tid] = fabsf(gmx - gmn);
    }
    __syncthreads();
    {
        int bb = tid >> 8, cc = (tid >> 3) & 31, pp = tid & 7;
        float a2 = 0.0f;
        #pragma unroll 1
        for (int l = 0; l < 4; ++l) {
            float val = vals[l];
            const float* Wr = p.opW + l * 4096 + cc * 128;
            int base = l * 128 + bb * 64;
            #pragma unroll 1
            for (int j = pp * 16; j < pp * 16 + 16; ++j) {
                float pv;
                if (j < 64) pv = sm_dg[base + j];
                else        pv = fmaxf(sm_off[base + j - 64], sm_dg[base + j - 64] - val);
                a2 = fmaf(Wr[j], pv, a2);
            }
        }
        psum[tid] = a2;
    }
    __syncthreads();
    if (tid < 64) {
        int bb = tid >> 5, cc = tid & 31;
        float a2 = 0.0f;
        #pragma unroll
        for (int l = 0; l < 4; ++l) a2 += p.opb[l * 32 + cc];
        #pragma unroll
        for (int pp = 0; pp < 8; ++pp) a2 += psum[bb * 256 + cc * 8 + pp];
        scores_s[tid] = a2;
    }
    __syncthreads();
    if (tid < 32) {
        float sA = scores_s[tid], sB = scores_s[32 + tid];
        float mu2 = 0.5f * (sA + sB);
        float va = 0.5f * ((sA - mu2) * (sA - mu2) + (sB - mu2) * (sB - mu2));
        float inv = rsqrtf(va + EPS);
        p.out[tid]      = (sA - mu2) * inv;
        p.out[32 + tid] = (sB - mu2) * inv;
    }
}

// ---------------------------------------------------------------------------
extern "C" void kernel_launch(void* const* d_in, const int* in_sizes, int n_in,
                              void* d_out, int out_size, void* d_ws, size_t ws_size,
                              hipStream_t stream) {
    Params prm;
    prm.ei    = (const int*)d_in[0];
    prm.batch = (const int*)d_in[1];
    prm.E     = in_sizes[0] / 2;
    prm.W0    = (const float*)d_in[2];
    prm.b0    = (const float*)d_in[3];
    prm.Ws    = (const float*)d_in[4];
    prm.bs    = (const float*)d_in[5];
    prm.ln_g  = (const float*)d_in[6];
    prm.ln_b  = (const float*)d_in[7];
    prm.fW0   = (const float*)d_in[8];
    prm.fb0   = (const float*)d_in[9];
    prm.fWs   = (const float*)d_in[10];
    prm.fbs   = (const float*)d_in[11];
    prm.fln_g = (const float*)d_in[12];
    prm.fln_b = (const float*)d_in[13];
    prm.opW   = (const float*)d_in[14];
    prm.opb   = (const float*)d_in[15];

    float* ws = (float*)d_ws;
    prm.hA    = ws;                   // 131072 each
    prm.qA    = prm.hA   + 131072;
    prm.hB    = prm.qA   + 131072;
    prm.qB    = prm.hB   + 131072;
    prm.hAT   = prm.qB   + 131072;
    prm.qAT   = prm.hAT  + 131072;
    prm.hBT   = prm.qAT  + 131072;
    prm.qBT   = prm.hBT  + 131072;
    prm.xbuf  = prm.qBT  + 131072;
    prm.Pmin  = prm.xbuf + 131072;    // 4*16384 each
    prm.Poff  = prm.Pmin + 65536;
    prm.Pdg   = prm.Poff + 65536;
    prm.bar   = (int*)(prm.Pdg + 65536);
    prm.out   = (float*)d_out;

    k0<<<256, 512, 0, stream>>>(prm);
    klayer<<<256, 512, 0, stream>>>(prm, 1, 0);
    klayer<<<256, 512, 0, stream>>>(prm, 2, 0);
    klayer<<<256, 512, 0, stream>>>(prm, 3, 1);
}

// Round 12
// 199.417 us; speedup vs baseline: 1.2138x; 1.0663x over previous
//
#include <hip/hip_runtime.h>
#include <math.h>

// Shapes fixed by the reference: B=2, N=32, L=4, ED=64, H=4, HD=16
#define EPS 1e-5f

#define AG_LOAD(p)     __hip_atomic_load((p), __ATOMIC_RELAXED, __HIP_MEMORY_SCOPE_AGENT)
#define AG_STORE(p, v) __hip_atomic_store((p), (v), __ATOMIC_RELAXED, __HIP_MEMORY_SCOPE_AGENT)

struct Params {
    const int* ei; const int* batch; int E;
    const float* W0; const float* b0; const float* Ws; const float* bs;
    const float* ln_g; const float* ln_b;
    const float* fW0; const float* fb0; const float* fWs; const float* fbs;
    const float* fln_g; const float* fln_b;
    const float* opW; const float* opb;
    float* hA; float* qA;    // h/q for layers 1 and 3
    float* hB; float* qB;    // layer 2
    float* xbuf;             // x rows, gtid-owned across dispatches
    float* WsT;              // transposed Ws[1],Ws[2]  : [2][64 j][64 c]
    float* fWsT;             // transposed fWs[0..2]    : [3][128 j][64 c]
    float* Pmin; float* Poff; float* Pdg;  // [4 layers][256 blocks][64 e]
    int* bar;                // tail counter (zeroed by k0)
    float* out;              // 64
};

// ---------------------------------------------------------------------------
// K0: weight transposes (for later dispatches) + adjacency slabs + closed-form
// layer 0 + pool partial 0 + lin -> h1/q1.  Exactly R8's k0 plus transposes.
__launch_bounds__(512, 1)
__global__ void k0(Params p) {
    const int tid  = threadIdx.x;
    const int blk  = blockIdx.x;
    const int gtid = blk * 512 + tid;
    const int c    = gtid & 63;
    const int d    = c & 15;
    const int rl   = tid >> 6;
    const int row  = gtid >> 6;
    const int y    = row & 31;
    const int r0     = blk * 8;
    const int b_blk  = r0 >> 10;
    const int xi_blk = (r0 >> 5) & 31;
    const int y0     = r0 & 31;
    const int rld    = xi_blk - y0;

    __shared__ float xslab[32];      // adj[b_blk, xi_blk, a]
    __shared__ float yslab[256];     // adj[b_blk, a, y0+j] at [a*8+j]
    __shared__ float xu[512];
    __shared__ float xrow[512];

    if (blk == 0 && tid == 0) p.bar[0] = 0;

    // ---- weight transposes for klayer dispatches (coalesced writes) ----
    if (gtid < 24576) {               // fWsT: [l][j][c] = fWs[l][c][j]
        int l = gtid >> 13, r = gtid & 8191;
        int j = r >> 6, c2 = r & 63;
        p.fWsT[gtid] = p.fWs[l * 8192 + c2 * 128 + j];
    } else if (gtid < 32768) {        // WsT: [l-1][j][c] = Ws[l][c][j], l=1,2
        int t = gtid - 24576;
        int l = t >> 12, r = t & 4095;
        int j = r >> 6, c2 = r & 63;
        p.WsT[t] = p.Ws[(l + 1) * 4096 + c2 * 64 + j];
    }

    if (tid < 32)  xslab[tid] = 0.0f;
    if (tid < 256) yslab[tid] = 0.0f;
    __syncthreads();
    #pragma unroll 1
    for (int e2 = tid; e2 < p.E; e2 += 512) {
        int e0 = p.ei[e2], e1 = p.ei[p.E + e2];
        int g  = p.batch[e0];
        if (g == b_blk) {
            int ls = e0 - g * 32, ld = e1 - g * 32;
            if (ls == xi_blk) atomicAdd(&xslab[ld], 1.0f);
            unsigned dy = (unsigned)(ld - y0);
            if (dy < 8u) atomicAdd(&yslab[ls * 8 + dy], 1.0f);
        }
    }
    __syncthreads();
    if (tid == 0) xslab[xi_blk] = 2.0f;
    if (tid < 8)  yslab[(y0 + tid) * 8 + tid] = 2.0f;   // diag a==y
    __syncthreads();

    // closed-form LN16 stats of rank-1 h = W*v + b
    const float gl = p.ln_g[d], bl = p.ln_b[d];
    float Wc = p.W0[c], bc = p.b0[c];
    float sW = Wc, sB = bc;
    #pragma unroll
    for (int m = 1; m < 16; m <<= 1) {
        sW += __shfl_xor(sW, m, 16);
        sB += __shfl_xor(sB, m, 16);
    }
    float Ac = Wc - sW * 0.0625f;
    float Bc = bc - sB * 0.0625f;
    float sAA = Ac * Ac, sAB = Ac * Bc, sBB = Bc * Bc;
    #pragma unroll
    for (int m = 1; m < 16; m <<= 1) {
        sAA += __shfl_xor(sAA, m, 16);
        sAB += __shfl_xor(sAB, m, 16);
        sBB += __shfl_xor(sBB, m, 16);
    }
    const float varW = sAA * 0.0625f, covWB = sAB * 0.0625f, varB = sBB * 0.0625f;
    const float adjv = xslab[y];

    // online-softmax attention from adj slabs (all LDS operands)
    float mrun = -1e30f, lrun = 0.0f, arun = 0.0f;
    #pragma unroll 1
    for (int a = 0; a < 32; ++a) {
        float vx = xslab[a];
        float vy = yslab[a * 8 + rl];
        float hx = fmaf(Wc, vx, bc);
        float hy = fmaf(Wc, vy, bc);
        float qx = fmaf(Ac, vx, Bc) *
                   rsqrtf(fmaf(fmaf(varW, vx, 2.0f * covWB), vx, varB) + EPS) * gl + bl;
        float qy = fmaf(Ac, vy, Bc) *
                   rsqrtf(fmaf(fmaf(varW, vy, 2.0f * covWB), vy, varB) + EPS) * gl + bl;
        float rdot = qx * qy;
        float pp   = hx * hy;
        float rsum = pp, rsq = pp * pp;
        #pragma unroll
        for (int m = 1; m < 16; m <<= 1) {
            rdot += __shfl_xor(rdot, m, 16);
            rsum += __shfl_xor(rsum, m, 16);
            rsq  += __shfl_xor(rsq,  m, 16);
        }
        float s     = rdot * 0.25f;
        float pmean = rsum * 0.0625f;
        float pvar  = fmaxf(rsq * 0.0625f - pmean * pmean, 0.0f);
        float nrm   = (pp - pmean) * rsqrtf(pvar + EPS) * gl;
        float nm  = fmaxf(mrun, s);
        float scl = __expf(mrun - nm);
        float e   = __expf(s - nm);
        lrun = lrun * scl + e;
        arun = arun * scl + e * nrm;
        mrun = nm;
    }
    xu[tid] = arun / lrun + bl;

    // fin (K=65) + LN64
    const float* Wr2 = p.fW0 + c * 65;
    float acc2 = fmaf(Wr2[0], adjv, p.fb0[c]);
    {
        const float* xw = xu + rl * 64;
        #pragma unroll 8
        for (int j = 0; j < 64; ++j) acc2 = fmaf(Wr2[1 + j], xw[j], acc2);
    }
    float t1 = acc2;
    #pragma unroll
    for (int m = 1; m < 64; m <<= 1) t1 += __shfl_xor(t1, m, 64);
    float mu = t1 * (1.0f / 64.0f);
    float dv2 = acc2 - mu;
    float t2 = dv2 * dv2;
    #pragma unroll
    for (int m = 1; m < 64; m <<= 1) t2 += __shfl_xor(t2, m, 64);
    float xnew = dv2 * rsqrtf(t2 * (1.0f / 64.0f) + EPS) * p.fln_g[c] + p.fln_b[c];
    xrow[tid]    = xnew;
    p.xbuf[gtid] = xnew;
    __syncthreads();

    // pool partial 0
    if (tid < 64) {
        float mn = 1e30f, off = -1e30f, dg = -1e30f;
        #pragma unroll
        for (int r2 = 0; r2 < 8; ++r2) {
            float v = xrow[r2 * 64 + tid];
            mn = fminf(mn, v);
            if (r2 == rld) dg = v; else off = fmaxf(off, v);
        }
        int o = blk * 64 + tid;
        p.Pmin[o] = mn; p.Poff[o] = off; p.Pdg[o] = dg;
    }

    // lin layer 1: h1 = x1 @ Ws[0].T + bs[0]; q1 = LN16 with ln[1]
    {
        const float4* W4 = (const float4*)(p.Ws + c * 64);
        const float4* X4 = (const float4*)(xrow + rl * 64);
        float acc = p.bs[c];
        #pragma unroll 4
        for (int j = 0; j < 16; ++j) {
            float4 w = W4[j], x = X4[j];
            acc += w.x * x.x + w.y * x.y + w.z * x.z + w.w * x.w;
        }
        p.hA[gtid] = acc;
        float s1 = acc;
        #pragma unroll
        for (int m = 1; m < 16; m <<= 1) s1 += __shfl_xor(s1, m, 16);
        float mean = s1 * 0.0625f;
        float dv = acc - mean;
        float s2 = dv * dv;
        #pragma unroll
        for (int m = 1; m < 16; m <<= 1) s2 += __shfl_xor(s2, m, 16);
        p.qA[gtid] = dv * rsqrtf(s2 * 0.0625f + EPS) * p.ln_g[16 + d] + p.ln_b[16 + d];
    }
}

// ---------------------------------------------------------------------------
// K(layer): attention + fin (transposed coalesced weights) + pool partial,
// then lin->h/q (transposed weights) or the tail-block epilogue.
__launch_bounds__(512, 1)
__global__ void klayer(Params p, int layer, int is_last) {
    const int tid  = threadIdx.x;
    const int blk  = blockIdx.x;
    const int gtid = blk * 512 + tid;
    const int c    = gtid & 63;
    const int d    = c & 15;
    const int rl   = tid >> 6;
    const int row  = gtid >> 6;
    const int y    = row & 31;
    const int b    = row >> 10;
    const int r0     = blk * 8;
    const int b_blk  = r0 >> 10;
    const int xi_blk = (r0 >> 5) & 31;
    const int y0     = r0 & 31;
    const int rld    = xi_blk - y0;
    const int slab_off = (b_blk * 1024 + xi_blk * 32) * 64;

    const float* hin = (layer == 2) ? p.hB : p.hA;
    const float* qin = (layer == 2) ? p.qB : p.qA;
    float* hout = (layer == 1) ? p.hB : p.hA;   // layer2 overwrites hA (h1 dead)
    float* qout = (layer == 1) ? p.qB : p.qA;

    __shared__ float qx_s[2048], hx_s[2048];
    __shared__ float xrow[512], xu[512];
    __shared__ float sm_mn[512], sm_off[512], sm_dg[512];
    __shared__ float psum[512];
    __shared__ float vals[4];
    __shared__ float scores_s[64];
    __shared__ int tailflag;

    // ---- staging: x row + x-slabs to LDS; y-scatter to registers ----
    float xv = p.xbuf[gtid];
    float4 qs = ((const float4*)(qin + slab_off))[tid];
    float4 hs = ((const float4*)(hin + slab_off))[tid];
    const float* qy = qin + (b * 1024 + y) * 64 + c;   // + a*2048
    const float* hy = hin + (b * 1024 + y) * 64 + c;
    float qyv[32], hyv[32];
    #pragma unroll
    for (int a = 0; a < 32; ++a) {
        qyv[a] = qy[a * 2048];
        hyv[a] = hy[a * 2048];
    }
    xrow[tid] = xv;
    ((float4*)qx_s)[tid] = qs;
    ((float4*)hx_s)[tid] = hs;
    __syncthreads();

    const float gl = p.ln_g[layer * 16 + d], bl = p.ln_b[layer * 16 + d];
    float sarr[32], narr[32];
    #pragma unroll
    for (int a = 0; a < 32; ++a) {
        float qxv = qx_s[a * 64 + c];
        float hxv = hx_s[a * 64 + c];
        float rdot = qxv * qyv[a];
        float pp   = hxv * hyv[a];
        float rsum = pp, rsq = pp * pp;
        #pragma unroll
        for (int m = 1; m < 16; m <<= 1) {
            rdot += __shfl_xor(rdot, m, 16);
            rsum += __shfl_xor(rsum, m, 16);
            rsq  += __shfl_xor(rsq,  m, 16);
        }
        sarr[a] = rdot * 0.25f;
        float pmean = rsum * 0.0625f;
        float pvar  = fmaxf(rsq * 0.0625f - pmean * pmean, 0.0f);
        narr[a] = (pp - pmean) * rsqrtf(pvar + EPS) * gl;
    }
    float mx = sarr[0];
    #pragma unroll
    for (int a = 1; a < 32; ++a) mx = fmaxf(mx, sarr[a]);
    float lsum = 0.0f, asum = 0.0f;
    #pragma unroll
    for (int a = 0; a < 32; ++a) {
        float ee = __expf(sarr[a] - mx);
        lsum += ee;
        asum = fmaf(ee, narr[a], asum);
    }
    xu[tid] = asum / lsum + bl;   // wave-local

    // ---- fin: y = concat([x, xu]) @ fW.T + fb, LN64 ----
    // TRANSPOSED weights: lane c reads fWsT[j*64+c] -> one coalesced 256B
    // load per wave per j; x[j] is an LDS broadcast (wave-uniform address).
    float acc2 = p.fbs[(layer - 1) * 64 + c];
    {
        const float* WT = p.fWsT + (layer - 1) * 8192 + c;
        const float* xa = xrow + rl * 64;
        const float* xb = xu + rl * 64;
        #pragma unroll 8
        for (int j = 0; j < 64; ++j) acc2 = fmaf(WT[j * 64], xa[j], acc2);
        WT += 64 * 64;
        #pragma unroll 8
        for (int j = 0; j < 64; ++j) acc2 = fmaf(WT[j * 64], xb[j], acc2);
    }
    float t1 = acc2;
    #pragma unroll
    for (int m = 1; m < 64; m <<= 1) t1 += __shfl_xor(t1, m, 64);
    float mu = t1 * (1.0f / 64.0f);
    float dv2 = acc2 - mu;
    float t2 = dv2 * dv2;
    #pragma unroll
    for (int m = 1; m < 64; m <<= 1) t2 += __shfl_xor(t2, m, 64);
    float xnew = dv2 * rsqrtf(t2 * (1.0f / 64.0f) + EPS) *
                 p.fln_g[layer * 64 + c] + p.fln_b[layer * 64 + c];
    xrow[tid] = xnew;            // same-wave overwrite after same-wave read
    if (!is_last) p.xbuf[gtid] = xnew;
    __syncthreads();

    // ---- pool partial for this layer ----
    if (tid < 64) {
        float mn = 1e30f, off = -1e30f, dg = -1e30f;
        #pragma unroll
        for (int r2 = 0; r2 < 8; ++r2) {
            float v = xrow[r2 * 64 + tid];
            mn = fminf(mn, v);
            if (r2 == rld) dg = v; else off = fmaxf(off, v);
        }
        int o = layer * 16384 + blk * 64 + tid;
        if (is_last) {   // must be LLC-visible within this dispatch (tail reads)
            AG_STORE(&p.Pmin[o], mn); AG_STORE(&p.Poff[o], off); AG_STORE(&p.Pdg[o], dg);
        } else {
            p.Pmin[o] = mn; p.Poff[o] = off; p.Pdg[o] = dg;
        }
    }

    if (!is_last) {
        // lin layer+1 with transposed Ws: h = x @ Ws[layer].T + bs[layer]
        const float* WT = p.WsT + (layer - 1) * 4096 + c;
        const float* xa = xrow + rl * 64;
        float acc = p.bs[layer * 64 + c];
        #pragma unroll 8
        for (int j = 0; j < 64; ++j) acc = fmaf(WT[j * 64], xa[j], acc);
        hout[gtid] = acc;
        float s1 = acc;
        #pragma unroll
        for (int m = 1; m < 16; m <<= 1) s1 += __shfl_xor(s1, m, 16);
        float mean = s1 * 0.0625f;
        float dv = acc - mean;
        float s2 = dv * dv;
        #pragma unroll
        for (int m = 1; m < 16; m <<= 1) s2 += __shfl_xor(s2, m, 16);
        qout[gtid] = dv * rsqrtf(s2 * 0.0625f + EPS) *
                     p.ln_g[(layer + 1) * 16 + d] + p.ln_b[(layer + 1) * 16 + d];
        return;
    }

    // ---- tail-block: 256th arriver runs the epilogue ----
    if (tid == 0) {
        int r = __hip_atomic_fetch_add(p.bar, 1, __ATOMIC_RELAXED,
                                       __HIP_MEMORY_SCOPE_AGENT);
        tailflag = (r == 255) ? 1 : 0;
    }
    __syncthreads();
    if (!tailflag) return;

    // ================= epilogue (tail block only) =================
    {
        int l = tid >> 7, bb = (tid >> 6) & 1, e = tid & 63;
        float mn = 1e30f, off = -1e30f, dg = -1e30f;
        int base = l * 16384 + bb * 128 * 64 + e;
        if (l == 3) {
            #pragma unroll 4
            for (int k = 0; k < 128; ++k) {
                int o = base + k * 64;
                mn  = fminf(mn,  AG_LOAD(&p.Pmin[o]));
                off = fmaxf(off, AG_LOAD(&p.Poff[o]));
                dg  = fmaxf(dg,  AG_LOAD(&p.Pdg[o]));
            }
        } else {
            #pragma unroll 4
            for (int k = 0; k < 128; ++k) {
                int o = base + k * 64;
                mn  = fminf(mn,  p.Pmin[o]);
                off = fmaxf(off, p.Poff[o]);
                dg  = fmaxf(dg,  p.Pdg[o]);
            }
        }
        sm_mn[tid] = mn; sm_off[tid] = off; sm_dg[tid] = dg;
    }
    __syncthreads();
    if (tid < 4) {
        float gmx = -1e30f, gmn = 1e30f;
        #pragma unroll 1
        for (int i2 = 0; i2 < 128; ++i2) {
            gmx = fmaxf(gmx, sm_dg[tid * 128 + i2]);
            gmn = fminf(gmn, sm_mn[tid * 128 + i2]);
        }
        vals[tid] = fabsf(gmx - gmn);
    }
    __syncthreads();
    {
        int bb = tid >> 8, cc = (tid >> 3) & 31, pp = tid & 7;
        float a2 = 0.0f;
        #pragma unroll 1
        for (int l = 0; l < 4; ++l) {
            float val = vals[l];
            const float* Wr = p.opW + l * 4096 + cc * 128;
            int base = l * 128 + bb * 64;
            #pragma unroll 1
            for (int j = pp * 16; j < pp * 16 + 16; ++j) {
                float pv;
                if (j < 64) pv = sm_dg[base + j];
                else        pv = fmaxf(sm_off[base + j - 64], sm_dg[base + j - 64] - val);
                a2 = fmaf(Wr[j], pv, a2);
            }
        }
        psum[tid] = a2;
    }
    __syncthreads();
    if (tid < 64) {
        int bb = tid >> 5, cc = tid & 31;
        float a2 = 0.0f;
        #pragma unroll
        for (int l = 0; l < 4; ++l) a2 += p.opb[l * 32 + cc];
        #pragma unroll
        for (int pp = 0; pp < 8; ++pp) a2 += psum[bb * 256 + cc * 8 + pp];
        scores_s[tid] = a2;
    }
    __syncthreads();
    if (tid < 32) {
        float sA = scores_s[tid], sB = scores_s[32 + tid];
        float mu2 = 0.5f * (sA + sB);
        float va = 0.5f * ((sA - mu2) * (sA - mu2) + (sB - mu2) * (sB - mu2));
        float inv = rsqrtf(va + EPS);
        p.out[tid]      = (sA - mu2) * inv;
        p.out[32 + tid] = (sB - mu2) * inv;
    }
}

// ---------------------------------------------------------------------------
extern "C" void kernel_launch(void* const* d_in, const int* in_sizes, int n_in,
                              void* d_out, int out_size, void* d_ws, size_t ws_size,
                              hipStream_t stream) {
    Params prm;
    prm.ei    = (const int*)d_in[0];
    prm.batch = (const int*)d_in[1];
    prm.E     = in_sizes[0] / 2;
    prm.W0    = (const float*)d_in[2];
    prm.b0    = (const float*)d_in[3];
    prm.Ws    = (const float*)d_in[4];
    prm.bs    = (const float*)d_in[5];
    prm.ln_g  = (const float*)d_in[6];
    prm.ln_b  = (const float*)d_in[7];
    prm.fW0   = (const float*)d_in[8];
    prm.fb0   = (const float*)d_in[9];
    prm.fWs   = (const float*)d_in[10];
    prm.fbs   = (const float*)d_in[11];
    prm.fln_g = (const float*)d_in[12];
    prm.fln_b = (const float*)d_in[13];
    prm.opW   = (const float*)d_in[14];
    prm.opb   = (const float*)d_in[15];

    float* ws = (float*)d_ws;
    prm.hA    = ws;                   // 131072 each
    prm.qA    = prm.hA   + 131072;
    prm.hB    = prm.qA   + 131072;
    prm.qB    = prm.hB   + 131072;
    prm.xbuf  = prm.qB   + 131072;
    prm.WsT   = prm.xbuf + 131072;    // 8192
    prm.fWsT  = prm.WsT  + 8192;      // 24576
    prm.Pmin  = prm.fWsT + 24576;     // 4*16384 each
    prm.Poff  = prm.Pmin + 65536;
    prm.Pdg   = prm.Poff + 65536;
    prm.bar   = (int*)(prm.Pdg + 65536);
    prm.out   = (float*)d_out;

    k0<<<256, 512, 0, stream>>>(prm);
    klayer<<<256, 512, 0, stream>>>(prm, 1, 0);
    klayer<<<256, 512, 0, stream>>>(prm, 2, 0);
    klayer<<<256, 512, 0, stream>>>(prm, 3, 1);
}